// Round 1
// baseline (167.859 us; speedup 1.0000x reference)
//
#include <hip/hip_runtime.h>

#define KK 8
#define DD 16
#define NN 32
#define TT 200
#define BB 2048

// per-k LDS slab strides, all == 4 (mod 32) floats so the <=8 distinct
// per-lane k values spread across all 32 banks -> conflict-free ds_read_b128
#define SC 516   // C slab stride (512 used)
#define SA 260   // A slab stride (256 used)
#define SE 36    // emission table stride (32 used)
#define SD 20    // dyn/init table stride (16 used)

__device__ __forceinline__ float dot16(const float* __restrict__ row,
                                       const float* __restrict__ z) {
  const float4* r4 = reinterpret_cast<const float4*>(row);
  float4 c0 = r4[0], c1 = r4[1], c2 = r4[2], c3 = r4[3];
  float a = c0.x * z[0], b = c0.y * z[1];
  a = fmaf(c0.z, z[2], a);  b = fmaf(c0.w, z[3], b);
  a = fmaf(c1.x, z[4], a);  b = fmaf(c1.y, z[5], b);
  a = fmaf(c1.z, z[6], a);  b = fmaf(c1.w, z[7], b);
  a = fmaf(c2.x, z[8], a);  b = fmaf(c2.y, z[9], b);
  a = fmaf(c2.z, z[10], a); b = fmaf(c2.w, z[11], b);
  a = fmaf(c3.x, z[12], a); b = fmaf(c3.y, z[13], b);
  a = fmaf(c3.z, z[14], a); b = fmaf(c3.w, z[15], b);
  return a + b;
}

// const-indexed register fill (keeps the array SROA-able into VGPRs)
__device__ __forceinline__ void load16(float* __restrict__ d,
                                       const float* __restrict__ s) {
  const float4* p = reinterpret_cast<const float4*>(s);
  float4 a0 = p[0], a1 = p[1], a2 = p[2], a3 = p[3];
  d[0] = a0.x;  d[1] = a0.y;  d[2] = a0.z;  d[3] = a0.w;
  d[4] = a1.x;  d[5] = a1.y;  d[6] = a1.z;  d[7] = a1.w;
  d[8] = a2.x;  d[9] = a2.y;  d[10] = a2.z; d[11] = a2.w;
  d[12] = a3.x; d[13] = a3.y; d[14] = a3.z; d[15] = a3.w;
}

// NOTE: no min-waves clause. __launch_bounds__(256,4) (forced <=128 VGPR
// -> guaranteed scratch spill) core-dumped under graph capture in an
// earlier round. Register pressure is controlled structurally instead:
//  - dyn/init loops are FULLY unrolled (so z0/z1/zp are const-indexed and
//    stay in VGPRs -- "#pragma unroll 2" left g runtime, which forces the
//    register arrays to scratch: rule #20)
//  - the fused emission loop is "#pragma unroll 1": its body already has
//    8 independent dot16s (32 ds_read_b128) of ILP for two items.
__global__ __launch_bounds__(256) void slds_lp_kernel(
    const int* __restrict__ dsts,      // [B,T]
    const float* __restrict__ zg,      // [B,T,D]
    const float* __restrict__ obsg,    // [B,T,N]
    const float* __restrict__ initlg,  // [K]
    const float* __restrict__ initloc, // [K,D]
    const float* __restrict__ initls,  // [K,D]
    const float* __restrict__ transg,  // [K,K]
    const float* __restrict__ Ag,      // [K,D,D]
    const float* __restrict__ dynoff,  // [K,D]
    const float* __restrict__ dynls,   // [K,D] (scale directly, NOT log)
    const float* __restrict__ Cg,      // [K,N,D]
    const float* __restrict__ emoff,   // [K,N]
    const float* __restrict__ emls,    // [K,N]
    float* __restrict__ out)           // [B]
{
  __shared__ __align__(16) float sC[KK * SC];
  __shared__ __align__(16) float sA[KK * SA];
  __shared__ __align__(16) float sEmOff[KK * SE];
  __shared__ __align__(16) float sEmInv[KK * SE];
  __shared__ __align__(16) float sDynOff[KK * SD];
  __shared__ __align__(16) float sDynInv[KK * SD];
  __shared__ __align__(16) float sInitLoc[KK * SD];
  __shared__ __align__(16) float sInitInv[KK * SD];
  __shared__ float sTrans[KK * KK];
  __shared__ float sEmConst[KK];
  __shared__ float sDynConst[KK];
  __shared__ float sInitLp[KK];

  const float HALF_LOG2PI = 0.91893853320467274178f;
  const int tid = threadIdx.x;

  // ---- stage params into LDS (transforms applied once per block) ----
  for (int i = tid; i < KK * NN * DD; i += 256) {   // 4096
    int k = i >> 9, r = i & 511;
    sC[k * SC + r] = Cg[i];
  }
  for (int i = tid; i < KK * DD * DD; i += 256) {   // 2048
    int k = i >> 8, r = i & 255;
    sA[k * SA + r] = Ag[i];
  }
  if (tid < KK * NN) {                              // 256
    int k = tid >> 5, n = tid & 31;
    sEmOff[k * SE + n] = emoff[tid];
    sEmInv[k * SE + n] = expf(-emls[tid]);
  }
  if (tid < KK * DD) {                              // 128
    int k = tid >> 4, d = tid & 15;
    sDynOff[k * SD + d] = dynoff[tid];
    sDynInv[k * SD + d] = 1.0f / dynls[tid];
    sInitLoc[k * SD + d] = initloc[tid];
    sInitInv[k * SD + d] = expf(-initls[tid]);
  }
  if (tid < KK * KK) {                              // 64: transition log-softmax
    int kr = tid >> 3;
    float mx = transg[kr * KK];
    for (int j = 1; j < KK; ++j) mx = fmaxf(mx, transg[kr * KK + j]);
    float ss = 0.f;
    for (int j = 0; j < KK; ++j) ss += expf(transg[kr * KK + j] - mx);
    sTrans[tid] = transg[tid] - (logf(ss) + mx);
  }
  if (tid < KK) {                                   // per-k constants
    int k = tid;
    float se = 0.f;
    for (int n = 0; n < NN; ++n) se -= emls[k * NN + n];
    sEmConst[k] = se - NN * HALF_LOG2PI;
    float sd = 0.f;
    for (int d = 0; d < DD; ++d) sd -= logf(dynls[k * DD + d]);
    sDynConst[k] = sd - DD * HALF_LOG2PI;
    float mx = initlg[0];
    for (int j = 1; j < KK; ++j) mx = fmaxf(mx, initlg[j]);
    float ss = 0.f;
    for (int j = 0; j < KK; ++j) ss += expf(initlg[j] - mx);
    float si = 0.f;
    for (int d = 0; d < DD; ++d) si -= initls[k * DD + d];
    sInitLp[k] = initlg[k] - (logf(ss) + mx) + si - DD * HALF_LOG2PI;
  }
  __syncthreads();

  // ---- one thread per (b, 2t)+(b, 2t+1) pair: 204800 pairs == 800x256,
  //      all blocks co-resident (3-4/CU vs the 5-block LDS limit) -> no
  //      second dispatch round; 2x independent work per thread for ILP ----
  const int p = blockIdx.x * 256 + tid;  // pair id
  const int b = p / 100;                 // 100 pairs per batch element
  const int tp = p - b * 100;
  const int item0 = b * TT + (tp << 1);

  const int2 s01 = *reinterpret_cast<const int2*>(dsts + item0);  // item0 even -> 8B aligned
  const int s0 = s01.x, s1 = s01.y;
  const int prevItem = (tp != 0) ? (item0 - 1) : item0;  // safe addr for tp==0
  const int sp = dsts[prevItem];

  float z0[16], z1[16], zp[16];
  load16(z0, zg + (size_t)item0 * DD);
  load16(z1, zg + (size_t)(item0 + 1) * DD);
  load16(zp, zg + (size_t)prevItem * DD);

  float lp;
  {
    // dynamics for item1 (prev state z0, always exists) fused with
    // dynamics-or-init for item0. FULL unroll: i0 is compile-time so
    // z0/z1/zp stay in registers. zp dies at the end of this block.
    const int a1b = s1 * SA;
    const int d14 = s1 * (SD / 4);
    float accD = 0.f, accE = 0.f;
    if (tp != 0) {
      const int a0b = s0 * SA;
      const int d04 = s0 * (SD / 4);
#pragma unroll
      for (int g = 0; g < 4; ++g) {
        const int i0 = g * 4;
        float4 off1 = reinterpret_cast<const float4*>(sDynOff)[d14 + g];
        float4 inv1 = reinterpret_cast<const float4*>(sDynInv)[d14 + g];
        float4 off0 = reinterpret_cast<const float4*>(sDynOff)[d04 + g];
        float4 inv0 = reinterpret_cast<const float4*>(sDynInv)[d04 + g];
        float m0 = dot16(&sA[a1b + (i0 + 0) * DD], z0) + off1.x;
        float m1 = dot16(&sA[a1b + (i0 + 1) * DD], z0) + off1.y;
        float m2 = dot16(&sA[a1b + (i0 + 2) * DD], z0) + off1.z;
        float m3 = dot16(&sA[a1b + (i0 + 3) * DD], z0) + off1.w;
        float n0 = dot16(&sA[a0b + (i0 + 0) * DD], zp) + off0.x;
        float n1 = dot16(&sA[a0b + (i0 + 1) * DD], zp) + off0.y;
        float n2 = dot16(&sA[a0b + (i0 + 2) * DD], zp) + off0.z;
        float n3 = dot16(&sA[a0b + (i0 + 3) * DD], zp) + off0.w;
        float e0 = (z1[i0 + 0] - m0) * inv1.x;
        float e1 = (z1[i0 + 1] - m1) * inv1.y;
        float e2 = (z1[i0 + 2] - m2) * inv1.z;
        float e3 = (z1[i0 + 3] - m3) * inv1.w;
        float f0 = (z0[i0 + 0] - n0) * inv0.x;
        float f1 = (z0[i0 + 1] - n1) * inv0.y;
        float f2 = (z0[i0 + 2] - n2) * inv0.z;
        float f3 = (z0[i0 + 3] - n3) * inv0.w;
        accD = fmaf(e0, e0, accD); accD = fmaf(e1, e1, accD);
        accD = fmaf(e2, e2, accD); accD = fmaf(e3, e3, accD);
        accE = fmaf(f0, f0, accE); accE = fmaf(f1, f1, accE);
        accE = fmaf(f2, f2, accE); accE = fmaf(f3, f3, accE);
      }
      lp = -0.5f * (accD + accE) + sDynConst[s1] + sDynConst[s0]
           + sTrans[s0 * KK + s1] + sTrans[sp * KK + s0];
    } else {
      const int i04 = s0 * (SD / 4);
#pragma unroll
      for (int g = 0; g < 4; ++g) {
        const int i0 = g * 4;
        float4 off1 = reinterpret_cast<const float4*>(sDynOff)[d14 + g];
        float4 inv1 = reinterpret_cast<const float4*>(sDynInv)[d14 + g];
        float4 loc = reinterpret_cast<const float4*>(sInitLoc)[i04 + g];
        float4 iv  = reinterpret_cast<const float4*>(sInitInv)[i04 + g];
        float m0 = dot16(&sA[a1b + (i0 + 0) * DD], z0) + off1.x;
        float m1 = dot16(&sA[a1b + (i0 + 1) * DD], z0) + off1.y;
        float m2 = dot16(&sA[a1b + (i0 + 2) * DD], z0) + off1.z;
        float m3 = dot16(&sA[a1b + (i0 + 3) * DD], z0) + off1.w;
        float e0 = (z1[i0 + 0] - m0) * inv1.x;
        float e1 = (z1[i0 + 1] - m1) * inv1.y;
        float e2 = (z1[i0 + 2] - m2) * inv1.z;
        float e3 = (z1[i0 + 3] - m3) * inv1.w;
        float f0 = (z0[i0 + 0] - loc.x) * iv.x;
        float f1 = (z0[i0 + 1] - loc.y) * iv.y;
        float f2 = (z0[i0 + 2] - loc.z) * iv.z;
        float f3 = (z0[i0 + 3] - loc.w) * iv.w;
        accD = fmaf(e0, e0, accD); accD = fmaf(e1, e1, accD);
        accD = fmaf(e2, e2, accD); accD = fmaf(e3, e3, accD);
        accE = fmaf(f0, f0, accE); accE = fmaf(f1, f1, accE);
        accE = fmaf(f2, f2, accE); accE = fmaf(f3, f3, accE);
      }
      lp = -0.5f * (accD + accE) + sDynConst[s1]
           + sTrans[s0 * KK + s1] + sInitLp[s0];
    }
  }

  // ---- emissions for both items, fused (obs rows are contiguous) ----
  {
    const float4* oA = reinterpret_cast<const float4*>(obsg + (size_t)item0 * NN);
    const int c0 = s0 * SC, c1 = s1 * SC;
    const int e04 = s0 * (SE / 4), e14 = s1 * (SE / 4);
    float accA = 0.f, accB = 0.f;
#pragma unroll 1
    for (int g = 0; g < 8; ++g) {
      float4 o0 = oA[g];
      float4 o1 = oA[8 + g];
      float4 offA = reinterpret_cast<const float4*>(sEmOff)[e04 + g];
      float4 invA = reinterpret_cast<const float4*>(sEmInv)[e04 + g];
      float4 offB = reinterpret_cast<const float4*>(sEmOff)[e14 + g];
      float4 invB = reinterpret_cast<const float4*>(sEmInv)[e14 + g];
      const int n0 = g * 4;
      float l0 = dot16(&sC[c0 + (n0 + 0) * DD], z0) + offA.x;
      float l1 = dot16(&sC[c0 + (n0 + 1) * DD], z0) + offA.y;
      float l2 = dot16(&sC[c0 + (n0 + 2) * DD], z0) + offA.z;
      float l3 = dot16(&sC[c0 + (n0 + 3) * DD], z0) + offA.w;
      float k0 = dot16(&sC[c1 + (n0 + 0) * DD], z1) + offB.x;
      float k1 = dot16(&sC[c1 + (n0 + 1) * DD], z1) + offB.y;
      float k2 = dot16(&sC[c1 + (n0 + 2) * DD], z1) + offB.z;
      float k3 = dot16(&sC[c1 + (n0 + 3) * DD], z1) + offB.w;
      float d0 = (o0.x - l0) * invA.x;
      float d1 = (o0.y - l1) * invA.y;
      float d2 = (o0.z - l2) * invA.z;
      float d3 = (o0.w - l3) * invA.w;
      float g0 = (o1.x - k0) * invB.x;
      float g1 = (o1.y - k1) * invB.y;
      float g2 = (o1.z - k2) * invB.z;
      float g3 = (o1.w - k3) * invB.w;
      accA = fmaf(d0, d0, accA); accA = fmaf(d1, d1, accA);
      accA = fmaf(d2, d2, accA); accA = fmaf(d3, d3, accA);
      accB = fmaf(g0, g0, accB); accB = fmaf(g1, g1, accB);
      accB = fmaf(g2, g2, accB); accB = fmaf(g3, g3, accB);
    }
    lp += -0.5f * (accA + accB) + sEmConst[s0] + sEmConst[s1];
  }

  // ---- wave-level segmented sum keyed by b (<=2 segments/wave), then atomic ----
  const int lane = tid & 63;
  float v = lp;
#pragma unroll
  for (int off = 1; off < 64; off <<= 1) {
    float ov = __shfl_up(v, off, 64);
    int obk = __shfl_up(b, off, 64);
    if (lane >= off && obk == b) v += ov;
  }
  int nb = __shfl_down(b, 1, 64);
  if (lane == 63 || nb != b) atomicAdd(&out[b], v);
}

extern "C" void kernel_launch(void* const* d_in, const int* in_sizes, int n_in,
                              void* d_out, int out_size, void* d_ws, size_t ws_size,
                              hipStream_t stream) {
  const int*   dsts    = (const int*)d_in[0];
  const float* zg      = (const float*)d_in[1];
  const float* obsg    = (const float*)d_in[2];
  const float* initlg  = (const float*)d_in[3];
  const float* initloc = (const float*)d_in[4];
  const float* initls  = (const float*)d_in[5];
  const float* transg  = (const float*)d_in[6];
  const float* Ag      = (const float*)d_in[7];
  const float* dynoff  = (const float*)d_in[8];
  const float* dynls   = (const float*)d_in[9];
  const float* Cg      = (const float*)d_in[10];
  const float* emoff   = (const float*)d_in[11];
  const float* emls    = (const float*)d_in[12];
  float* out = (float*)d_out;

  hipMemsetAsync(d_out, 0, BB * sizeof(float), stream);

  // 800 blocks x 256 threads == exactly B*T/2 pairs, one pair per thread.
  // All 800 blocks co-resident (LDS allows 5/CU) -> single dispatch round.
  slds_lp_kernel<<<800, 256, 0, stream>>>(dsts, zg, obsg, initlg, initloc,
                                          initls, transg, Ag, dynoff, dynls,
                                          Cg, emoff, emls, out);
}

// Round 2
// 145.789 us; speedup vs baseline: 1.1514x; 1.1514x over previous
//
#include <hip/hip_runtime.h>

#define KK 8
#define DD 16
#define NN 32
#define TT 200
#define BB 2048

// per-k LDS slab strides, all == 4 (mod 32) floats so the <=8 distinct
// per-lane k values spread across all 32 banks -> conflict-free ds_read_b128
#define SC 516   // C slab stride (512 used)
#define SA 260   // A slab stride (256 used)
#define SE 36    // emission table stride (32 used)
#define SD 20    // dyn/init table stride (16 used)

__device__ __forceinline__ float dot16(const float* __restrict__ row,
                                       const float* __restrict__ z) {
  const float4* r4 = reinterpret_cast<const float4*>(row);
  float4 c0 = r4[0], c1 = r4[1], c2 = r4[2], c3 = r4[3];
  float a = c0.x * z[0], b = c0.y * z[1];
  a = fmaf(c0.z, z[2], a);  b = fmaf(c0.w, z[3], b);
  a = fmaf(c1.x, z[4], a);  b = fmaf(c1.y, z[5], b);
  a = fmaf(c1.z, z[6], a);  b = fmaf(c1.w, z[7], b);
  a = fmaf(c2.x, z[8], a);  b = fmaf(c2.y, z[9], b);
  a = fmaf(c2.z, z[10], a); b = fmaf(c2.w, z[11], b);
  a = fmaf(c3.x, z[12], a); b = fmaf(c3.y, z[13], b);
  a = fmaf(c3.z, z[14], a); b = fmaf(c3.w, z[15], b);
  return a + b;
}

// const-indexed register fill (keeps the array SROA-able into VGPRs)
__device__ __forceinline__ void load16(float* __restrict__ d,
                                       const float* __restrict__ s) {
  const float4* p = reinterpret_cast<const float4*>(s);
  float4 a0 = p[0], a1 = p[1], a2 = p[2], a3 = p[3];
  d[0] = a0.x;  d[1] = a0.y;  d[2] = a0.z;  d[3] = a0.w;
  d[4] = a1.x;  d[5] = a1.y;  d[6] = a1.z;  d[7] = a1.w;
  d[8] = a2.x;  d[9] = a2.y;  d[10] = a2.z; d[11] = a2.w;
  d[12] = a3.x; d[13] = a3.y; d[14] = a3.z; d[15] = a3.w;
}

// Occupancy ledger (MUST hold): LDS 30208 B -> 5 blocks/CU; need VGPR <= 102
// so 5 waves/SIMD fit -> 20 waves/CU, same as the 47us baseline but with
// z/zp in REGISTERS instead of scratch (rule #20: any runtime index on the
// array sends the WHOLE array to scratch, and 1280 threads/CU x 64 B scratch
// = 80 KB > 32 KB L1 -> every dot16 chained on ~200cy L2 scratch loads).
// Therefore: dyn/init loops are FULLY unrolled (compile-time indices only);
// emission loop stays "#pragma unroll 2" (fat LDS batches, bounded VGPR).
// No min-waves clause in __launch_bounds__: forcing a VGPR cap spills, and
// spill+graph-capture core-dumped in an earlier round.
__global__ __launch_bounds__(256) void slds_lp_kernel(
    const int* __restrict__ dsts,      // [B,T]
    const float* __restrict__ zg,      // [B,T,D]
    const float* __restrict__ obsg,    // [B,T,N]
    const float* __restrict__ initlg,  // [K]
    const float* __restrict__ initloc, // [K,D]
    const float* __restrict__ initls,  // [K,D]
    const float* __restrict__ transg,  // [K,K]
    const float* __restrict__ Ag,      // [K,D,D]
    const float* __restrict__ dynoff,  // [K,D]
    const float* __restrict__ dynls,   // [K,D] (scale directly, NOT log)
    const float* __restrict__ Cg,      // [K,N,D]
    const float* __restrict__ emoff,   // [K,N]
    const float* __restrict__ emls,    // [K,N]
    float* __restrict__ out)           // [B]
{
  __shared__ __align__(16) float sC[KK * SC];
  __shared__ __align__(16) float sA[KK * SA];
  __shared__ __align__(16) float sEmOff[KK * SE];
  __shared__ __align__(16) float sEmInv[KK * SE];
  __shared__ __align__(16) float sDynOff[KK * SD];
  __shared__ __align__(16) float sDynInv[KK * SD];
  __shared__ __align__(16) float sInitLoc[KK * SD];
  __shared__ __align__(16) float sInitInv[KK * SD];
  __shared__ float sTrans[KK * KK];
  __shared__ float sEmConst[KK];
  __shared__ float sDynConst[KK];
  __shared__ float sInitLp[KK];

  const float HALF_LOG2PI = 0.91893853320467274178f;
  const int tid = threadIdx.x;

  // ---- stage params into LDS (transforms applied once per block) ----
  for (int i = tid; i < KK * NN * DD; i += 256) {   // 4096
    int k = i >> 9, r = i & 511;
    sC[k * SC + r] = Cg[i];
  }
  for (int i = tid; i < KK * DD * DD; i += 256) {   // 2048
    int k = i >> 8, r = i & 255;
    sA[k * SA + r] = Ag[i];
  }
  if (tid < KK * NN) {                              // 256
    int k = tid >> 5, n = tid & 31;
    sEmOff[k * SE + n] = emoff[tid];
    sEmInv[k * SE + n] = expf(-emls[tid]);
  }
  if (tid < KK * DD) {                              // 128
    int k = tid >> 4, d = tid & 15;
    sDynOff[k * SD + d] = dynoff[tid];
    sDynInv[k * SD + d] = 1.0f / dynls[tid];
    sInitLoc[k * SD + d] = initloc[tid];
    sInitInv[k * SD + d] = expf(-initls[tid]);
  }
  if (tid < KK * KK) {                              // 64: transition log-softmax
    int kr = tid >> 3;
    float mx = transg[kr * KK];
    for (int j = 1; j < KK; ++j) mx = fmaxf(mx, transg[kr * KK + j]);
    float ss = 0.f;
    for (int j = 0; j < KK; ++j) ss += expf(transg[kr * KK + j] - mx);
    sTrans[tid] = transg[tid] - (logf(ss) + mx);
  }
  if (tid < KK) {                                   // per-k constants
    int k = tid;
    float se = 0.f;
    for (int n = 0; n < NN; ++n) se -= emls[k * NN + n];
    sEmConst[k] = se - NN * HALF_LOG2PI;
    float sd = 0.f;
    for (int d = 0; d < DD; ++d) sd -= logf(dynls[k * DD + d]);
    sDynConst[k] = sd - DD * HALF_LOG2PI;
    float mx = initlg[0];
    for (int j = 1; j < KK; ++j) mx = fmaxf(mx, initlg[j]);
    float ss = 0.f;
    for (int j = 0; j < KK; ++j) ss += expf(initlg[j] - mx);
    float si = 0.f;
    for (int d = 0; d < DD; ++d) si -= initls[k * DD + d];
    sInitLp[k] = initlg[k] - (logf(ss) + mx) + si - DD * HALF_LOG2PI;
  }
  __syncthreads();

  // ---- one thread per (b,t) item: 409600 items == 1600x256 exactly ----
  const int item = blockIdx.x * 256 + tid;
  const int b = item / TT;
  const int t = item - b * TT;

  float z[16];
  load16(z, zg + (size_t)item * DD);
  const int s = dsts[item];

  // emissions -- unroll 2: two groups of {1 obs float4 + 2 table float4 +
  // 8 C float4} LDS/global loads in flight per iteration, dual accumulators
  const float4* o4 = reinterpret_cast<const float4*>(obsg + (size_t)item * NN);
  const int cb = s * SC;
  const int eb4 = s * (SE / 4);
  float acc = 0.f;
#pragma unroll 2
  for (int g = 0; g < 8; ++g) {
    float4 o = o4[g];
    float4 off = reinterpret_cast<const float4*>(sEmOff)[eb4 + g];
    float4 inv = reinterpret_cast<const float4*>(sEmInv)[eb4 + g];
    int n0 = g * 4;
    float l0 = dot16(&sC[cb + (n0 + 0) * DD], z) + off.x;
    float l1 = dot16(&sC[cb + (n0 + 1) * DD], z) + off.y;
    float l2 = dot16(&sC[cb + (n0 + 2) * DD], z) + off.z;
    float l3 = dot16(&sC[cb + (n0 + 3) * DD], z) + off.w;
    float d0 = (o.x - l0) * inv.x;
    float d1 = (o.y - l1) * inv.y;
    float d2 = (o.z - l2) * inv.z;
    float d3 = (o.w - l3) * inv.w;
    acc = fmaf(d0, d0, acc); acc = fmaf(d1, d1, acc);
    acc = fmaf(d2, d2, acc); acc = fmaf(d3, d3, acc);
  }
  float lp = -0.5f * acc + sEmConst[s];

  if (t != 0) {
    const int sp = dsts[item - 1];
    float zp[16];
    load16(zp, zg + (size_t)(item - 1) * DD);
    const int ab = s * SA;
    const int db4 = s * (SD / 4);
    float a2acc = 0.f;
    // FULL unroll: i0 compile-time -> z/zp stay in VGPRs (rule #20)
#pragma unroll
    for (int g = 0; g < 4; ++g) {
      const int i0 = g * 4;
      float4 off = reinterpret_cast<const float4*>(sDynOff)[db4 + g];
      float4 inv = reinterpret_cast<const float4*>(sDynInv)[db4 + g];
      float l0 = dot16(&sA[ab + (i0 + 0) * DD], zp) + off.x;
      float l1 = dot16(&sA[ab + (i0 + 1) * DD], zp) + off.y;
      float l2 = dot16(&sA[ab + (i0 + 2) * DD], zp) + off.z;
      float l3 = dot16(&sA[ab + (i0 + 3) * DD], zp) + off.w;
      float d0 = (z[i0 + 0] - l0) * inv.x;
      float d1 = (z[i0 + 1] - l1) * inv.y;
      float d2 = (z[i0 + 2] - l2) * inv.z;
      float d3 = (z[i0 + 3] - l3) * inv.w;
      a2acc = fmaf(d0, d0, a2acc); a2acc = fmaf(d1, d1, a2acc);
      a2acc = fmaf(d2, d2, a2acc); a2acc = fmaf(d3, d3, a2acc);
    }
    lp += -0.5f * a2acc + sDynConst[s] + sTrans[sp * KK + s];
  } else {
    const int ib4 = s * (SD / 4);
    float a2acc = 0.f;
    // FULL unroll: i0 compile-time -> z stays in VGPRs
#pragma unroll
    for (int g = 0; g < 4; ++g) {
      const int i0 = g * 4;
      float4 loc = reinterpret_cast<const float4*>(sInitLoc)[ib4 + g];
      float4 inv = reinterpret_cast<const float4*>(sInitInv)[ib4 + g];
      float d0 = (z[i0 + 0] - loc.x) * inv.x;
      float d1 = (z[i0 + 1] - loc.y) * inv.y;
      float d2 = (z[i0 + 2] - loc.z) * inv.z;
      float d3 = (z[i0 + 3] - loc.w) * inv.w;
      a2acc = fmaf(d0, d0, a2acc); a2acc = fmaf(d1, d1, a2acc);
      a2acc = fmaf(d2, d2, a2acc); a2acc = fmaf(d3, d3, a2acc);
    }
    lp += -0.5f * a2acc + sInitLp[s];
  }

  // ---- wave-level segmented sum keyed by b (<=2 segments/wave), then atomic ----
  const int lane = tid & 63;
  float v = lp;
#pragma unroll
  for (int off = 1; off < 64; off <<= 1) {
    float ov = __shfl_up(v, off, 64);
    int obk = __shfl_up(b, off, 64);
    if (lane >= off && obk == b) v += ov;
  }
  int nb = __shfl_down(b, 1, 64);
  if (lane == 63 || nb != b) atomicAdd(&out[b], v);
}

extern "C" void kernel_launch(void* const* d_in, const int* in_sizes, int n_in,
                              void* d_out, int out_size, void* d_ws, size_t ws_size,
                              hipStream_t stream) {
  const int*   dsts    = (const int*)d_in[0];
  const float* zg      = (const float*)d_in[1];
  const float* obsg    = (const float*)d_in[2];
  const float* initlg  = (const float*)d_in[3];
  const float* initloc = (const float*)d_in[4];
  const float* initls  = (const float*)d_in[5];
  const float* transg  = (const float*)d_in[6];
  const float* Ag      = (const float*)d_in[7];
  const float* dynoff  = (const float*)d_in[8];
  const float* dynls   = (const float*)d_in[9];
  const float* Cg      = (const float*)d_in[10];
  const float* emoff   = (const float*)d_in[11];
  const float* emls    = (const float*)d_in[12];
  float* out = (float*)d_out;

  hipMemsetAsync(d_out, 0, BB * sizeof(float), stream);

  // 1600 blocks x 256 threads == exactly B*T items, one per thread
  slds_lp_kernel<<<1600, 256, 0, stream>>>(dsts, zg, obsg, initlg, initloc,
                                           initls, transg, Ag, dynoff, dynls,
                                           Cg, emoff, emls, out);
}

// Round 3
// 142.540 us; speedup vs baseline: 1.1776x; 1.0228x over previous
//
#include <hip/hip_runtime.h>

#define KK 8
#define DD 16
#define NN 32
#define TT 200
#define BB 2048

// per-k LDS slab strides, all == 4 (mod 32) floats so the <=8 distinct
// per-lane k values spread across all 32 banks -> conflict-free ds_read_b128
#define SC 516   // C slab stride (512 used)
#define SA 260   // A slab stride (256 used)
#define SE 36    // emission table stride (32 used)
#define SD 20    // dyn/init table stride (16 used)

__device__ __forceinline__ float dot16(const float* __restrict__ row,
                                       const float* __restrict__ z) {
  const float4* r4 = reinterpret_cast<const float4*>(row);
  float4 c0 = r4[0], c1 = r4[1], c2 = r4[2], c3 = r4[3];
  float a = c0.x * z[0], b = c0.y * z[1];
  a = fmaf(c0.z, z[2], a);  b = fmaf(c0.w, z[3], b);
  a = fmaf(c1.x, z[4], a);  b = fmaf(c1.y, z[5], b);
  a = fmaf(c1.z, z[6], a);  b = fmaf(c1.w, z[7], b);
  a = fmaf(c2.x, z[8], a);  b = fmaf(c2.y, z[9], b);
  a = fmaf(c2.z, z[10], a); b = fmaf(c2.w, z[11], b);
  a = fmaf(c3.x, z[12], a); b = fmaf(c3.y, z[13], b);
  a = fmaf(c3.z, z[14], a); b = fmaf(c3.w, z[15], b);
  return a + b;
}

// const-indexed register fill (keeps the array SROA-able into VGPRs)
__device__ __forceinline__ void load16(float* __restrict__ d,
                                       const float* __restrict__ s) {
  const float4* p = reinterpret_cast<const float4*>(s);
  float4 a0 = p[0], a1 = p[1], a2 = p[2], a3 = p[3];
  d[0] = a0.x;  d[1] = a0.y;  d[2] = a0.z;  d[3] = a0.w;
  d[4] = a1.x;  d[5] = a1.y;  d[6] = a1.z;  d[7] = a1.w;
  d[8] = a2.x;  d[9] = a2.y;  d[10] = a2.z; d[11] = a2.w;
  d[12] = a3.x; d[13] = a3.y; d[14] = a3.z; d[15] = a3.w;
}

// Occupancy ledger (MUST hold): VGPR allocation is power-of-2-quantized
// (waves/SIMD halve at 64/128/256 -- m69). Round-2's VGPR=68 silently
// halved residency to 4 waves/SIMD (16 waves/CU, 4 blocks/CU). Target here:
// VGPR <= 64 -> then LDS (30208 B -> 5 blocks/CU) is the limiter at
// 20 waves/CU. The emission loop is unroll(1) for exactly this reason:
// unroll(2)'s second in-flight iteration (~16 extra live VGPRs) is what
// pushed us to 68. Dyn/init loops stay FULLY unrolled (compile-time
// indices keep z/zp in VGPRs -- rule #20; their transient pressure does
// not overlap the emission loop's).
// Grid: 1280 blocks x 320 items each (strided 256) == exactly B*T, work
// perfectly uniform per CU (5 blocks x 320 items), single residency round,
// no lumpy low-occupancy tail (round 2's 1600-block grid ran 1.56 rounds).
__global__ __launch_bounds__(256) void slds_lp_kernel(
    const int* __restrict__ dsts,      // [B,T]
    const float* __restrict__ zg,      // [B,T,D]
    const float* __restrict__ obsg,    // [B,T,N]
    const float* __restrict__ initlg,  // [K]
    const float* __restrict__ initloc, // [K,D]
    const float* __restrict__ initls,  // [K,D]
    const float* __restrict__ transg,  // [K,K]
    const float* __restrict__ Ag,      // [K,D,D]
    const float* __restrict__ dynoff,  // [K,D]
    const float* __restrict__ dynls,   // [K,D] (scale directly, NOT log)
    const float* __restrict__ Cg,      // [K,N,D]
    const float* __restrict__ emoff,   // [K,N]
    const float* __restrict__ emls,    // [K,N]
    float* __restrict__ out)           // [B]
{
  __shared__ __align__(16) float sC[KK * SC];
  __shared__ __align__(16) float sA[KK * SA];
  __shared__ __align__(16) float sEmOff[KK * SE];
  __shared__ __align__(16) float sEmInv[KK * SE];
  __shared__ __align__(16) float sDynOff[KK * SD];
  __shared__ __align__(16) float sDynInv[KK * SD];
  __shared__ __align__(16) float sInitLoc[KK * SD];
  __shared__ __align__(16) float sInitInv[KK * SD];
  __shared__ float sTrans[KK * KK];
  __shared__ float sEmConst[KK];
  __shared__ float sDynConst[KK];
  __shared__ float sInitLp[KK];

  const float HALF_LOG2PI = 0.91893853320467274178f;
  const int tid = threadIdx.x;

  // ---- stage params into LDS (transforms applied once per block) ----
  for (int i = tid; i < KK * NN * DD; i += 256) {   // 4096
    int k = i >> 9, r = i & 511;
    sC[k * SC + r] = Cg[i];
  }
  for (int i = tid; i < KK * DD * DD; i += 256) {   // 2048
    int k = i >> 8, r = i & 255;
    sA[k * SA + r] = Ag[i];
  }
  if (tid < KK * NN) {                              // 256
    int k = tid >> 5, n = tid & 31;
    sEmOff[k * SE + n] = emoff[tid];
    sEmInv[k * SE + n] = expf(-emls[tid]);
  }
  if (tid < KK * DD) {                              // 128
    int k = tid >> 4, d = tid & 15;
    sDynOff[k * SD + d] = dynoff[tid];
    sDynInv[k * SD + d] = 1.0f / dynls[tid];
    sInitLoc[k * SD + d] = initloc[tid];
    sInitInv[k * SD + d] = expf(-initls[tid]);
  }
  if (tid < KK * KK) {                              // 64: transition log-softmax
    int kr = tid >> 3;
    float mx = transg[kr * KK];
    for (int j = 1; j < KK; ++j) mx = fmaxf(mx, transg[kr * KK + j]);
    float ss = 0.f;
    for (int j = 0; j < KK; ++j) ss += expf(transg[kr * KK + j] - mx);
    sTrans[tid] = transg[tid] - (logf(ss) + mx);
  }
  if (tid < KK) {                                   // per-k constants
    int k = tid;
    float se = 0.f;
    for (int n = 0; n < NN; ++n) se -= emls[k * NN + n];
    sEmConst[k] = se - NN * HALF_LOG2PI;
    float sd = 0.f;
    for (int d = 0; d < DD; ++d) sd -= logf(dynls[k * DD + d]);
    sDynConst[k] = sd - DD * HALF_LOG2PI;
    float mx = initlg[0];
    for (int j = 1; j < KK; ++j) mx = fmaxf(mx, initlg[j]);
    float ss = 0.f;
    for (int j = 0; j < KK; ++j) ss += expf(initlg[j] - mx);
    float si = 0.f;
    for (int d = 0; d < DD; ++d) si -= initls[k * DD + d];
    sInitLp[k] = initlg[k] - (logf(ss) + mx) + si - DD * HALF_LOG2PI;
  }
  __syncthreads();

  // ---- block bk owns items [bk*320, bk*320+320): pass 1 all 4 waves,
  //      pass 2 only wave 0 (ofs=tid+256 < 320 -> tid < 64), waves 1-3
  //      skip via execz. Uniform across all 1280 blocks. ----
  const int base = blockIdx.x * 320;
  for (int ofs = tid; ofs < 320; ofs += 256) {
    const int item = base + ofs;
    const int b = item / TT;
    const int t = item - b * TT;

    float z[16];
    load16(z, zg + (size_t)item * DD);
    const int s = dsts[item];

    // emissions -- unroll 1: 4 dot16s (16 ds_read_b128) of in-iteration
    // ILP; second-iteration overlap traded away to stay under 64 VGPR
    const float4* o4 = reinterpret_cast<const float4*>(obsg + (size_t)item * NN);
    const int cb = s * SC;
    const int eb4 = s * (SE / 4);
    float acc = 0.f;
#pragma unroll 1
    for (int g = 0; g < 8; ++g) {
      float4 o = o4[g];
      float4 off = reinterpret_cast<const float4*>(sEmOff)[eb4 + g];
      float4 inv = reinterpret_cast<const float4*>(sEmInv)[eb4 + g];
      int n0 = g * 4;
      float l0 = dot16(&sC[cb + (n0 + 0) * DD], z) + off.x;
      float l1 = dot16(&sC[cb + (n0 + 1) * DD], z) + off.y;
      float l2 = dot16(&sC[cb + (n0 + 2) * DD], z) + off.z;
      float l3 = dot16(&sC[cb + (n0 + 3) * DD], z) + off.w;
      float d0 = (o.x - l0) * inv.x;
      float d1 = (o.y - l1) * inv.y;
      float d2 = (o.z - l2) * inv.z;
      float d3 = (o.w - l3) * inv.w;
      acc = fmaf(d0, d0, acc); acc = fmaf(d1, d1, acc);
      acc = fmaf(d2, d2, acc); acc = fmaf(d3, d3, acc);
    }
    float lp = -0.5f * acc + sEmConst[s];

    if (t != 0) {
      const int sp = dsts[item - 1];
      float zp[16];
      load16(zp, zg + (size_t)(item - 1) * DD);
      const int ab = s * SA;
      const int db4 = s * (SD / 4);
      float a2acc = 0.f;
      // FULL unroll: i0 compile-time -> z/zp stay in VGPRs (rule #20)
#pragma unroll
      for (int g = 0; g < 4; ++g) {
        const int i0 = g * 4;
        float4 off = reinterpret_cast<const float4*>(sDynOff)[db4 + g];
        float4 inv = reinterpret_cast<const float4*>(sDynInv)[db4 + g];
        float l0 = dot16(&sA[ab + (i0 + 0) * DD], zp) + off.x;
        float l1 = dot16(&sA[ab + (i0 + 1) * DD], zp) + off.y;
        float l2 = dot16(&sA[ab + (i0 + 2) * DD], zp) + off.z;
        float l3 = dot16(&sA[ab + (i0 + 3) * DD], zp) + off.w;
        float d0 = (z[i0 + 0] - l0) * inv.x;
        float d1 = (z[i0 + 1] - l1) * inv.y;
        float d2 = (z[i0 + 2] - l2) * inv.z;
        float d3 = (z[i0 + 3] - l3) * inv.w;
        a2acc = fmaf(d0, d0, a2acc); a2acc = fmaf(d1, d1, a2acc);
        a2acc = fmaf(d2, d2, a2acc); a2acc = fmaf(d3, d3, a2acc);
      }
      lp += -0.5f * a2acc + sDynConst[s] + sTrans[sp * KK + s];
    } else {
      const int ib4 = s * (SD / 4);
      float a2acc = 0.f;
      // FULL unroll: i0 compile-time -> z stays in VGPRs
#pragma unroll
      for (int g = 0; g < 4; ++g) {
        const int i0 = g * 4;
        float4 loc = reinterpret_cast<const float4*>(sInitLoc)[ib4 + g];
        float4 inv = reinterpret_cast<const float4*>(sInitInv)[ib4 + g];
        float d0 = (z[i0 + 0] - loc.x) * inv.x;
        float d1 = (z[i0 + 1] - loc.y) * inv.y;
        float d2 = (z[i0 + 2] - loc.z) * inv.z;
        float d3 = (z[i0 + 3] - loc.w) * inv.w;
        a2acc = fmaf(d0, d0, a2acc); a2acc = fmaf(d1, d1, a2acc);
        a2acc = fmaf(d2, d2, a2acc); a2acc = fmaf(d3, d3, a2acc);
      }
      lp += -0.5f * a2acc + sInitLp[s];
    }

    // ---- wave-level segmented sum keyed by b (<=2 segments/wave), then atomic ----
    const int lane = tid & 63;
    float v = lp;
#pragma unroll
    for (int off = 1; off < 64; off <<= 1) {
      float ov = __shfl_up(v, off, 64);
      int obk = __shfl_up(b, off, 64);
      if (lane >= off && obk == b) v += ov;
    }
    int nb = __shfl_down(b, 1, 64);
    if (lane == 63 || nb != b) atomicAdd(&out[b], v);
  }
}

extern "C" void kernel_launch(void* const* d_in, const int* in_sizes, int n_in,
                              void* d_out, int out_size, void* d_ws, size_t ws_size,
                              hipStream_t stream) {
  const int*   dsts    = (const int*)d_in[0];
  const float* zg      = (const float*)d_in[1];
  const float* obsg    = (const float*)d_in[2];
  const float* initlg  = (const float*)d_in[3];
  const float* initloc = (const float*)d_in[4];
  const float* initls  = (const float*)d_in[5];
  const float* transg  = (const float*)d_in[6];
  const float* Ag      = (const float*)d_in[7];
  const float* dynoff  = (const float*)d_in[8];
  const float* dynls   = (const float*)d_in[9];
  const float* Cg      = (const float*)d_in[10];
  const float* emoff   = (const float*)d_in[11];
  const float* emls    = (const float*)d_in[12];
  float* out = (float*)d_out;

  hipMemsetAsync(d_out, 0, BB * sizeof(float), stream);

  // 1280 blocks x 320 items each == exactly B*T; uniform 5 blocks/CU
  slds_lp_kernel<<<1280, 256, 0, stream>>>(dsts, zg, obsg, initlg, initloc,
                                           initls, transg, Ag, dynoff, dynls,
                                           Cg, emoff, emls, out);
}